// Round 4
// baseline (633.892 us; speedup 1.0000x reference)
//
#include <hip/hip_runtime.h>
#include <hip/hip_fp16.h>
#include <math.h>

typedef _Float16 half4_t __attribute__((ext_vector_type(4)));
typedef _Float16 half8_t __attribute__((ext_vector_type(8)));
typedef float float4_t __attribute__((ext_vector_type(4)));

static constexpr int DMODEL = 1024;
static constexpr int SLEN   = 2048;
static constexpr int NHEADS = 16;
static constexpr int MTOT   = 4096;   // B * S

// ---------------- fused f32 -> f16 convert (x + all 5 weights) ----------------
__global__ __launch_bounds__(256) void cvt_all_kernel(
    const float* __restrict__ x,
    const float* __restrict__ Wq, const float* __restrict__ Wk,
    const float* __restrict__ Wv, const float* __restrict__ Wo,
    const float* __restrict__ Wm1,
    _Float16* __restrict__ xh, _Float16* __restrict__ wqh,
    _Float16* __restrict__ wkh, _Float16* __restrict__ wvh,
    _Float16* __restrict__ woh, _Float16* __restrict__ wm1h) {
  int bx = blockIdx.x;
  const float* src; _Float16* dst; int lb;
  if (blockIdx.y == 0) {
    if (bx >= 4096) return;
    src = x; dst = xh; lb = bx;
  } else {
    if (bx < 1024)      { src = Wq;  dst = wqh;  lb = bx; }
    else if (bx < 2048) { src = Wk;  dst = wkh;  lb = bx - 1024; }
    else if (bx < 3072) { src = Wv;  dst = wvh;  lb = bx - 2048; }
    else if (bx < 4096) { src = Wo;  dst = woh;  lb = bx - 3072; }
    else                { src = Wm1; dst = wm1h; lb = bx - 4096; }
  }
  int i = lb * 256 + threadIdx.x;
  float4_t v = ((const float4_t*)src)[i];
  half4_t h;
  h[0] = (_Float16)v[0]; h[1] = (_Float16)v[1];
  h[2] = (_Float16)v[2]; h[3] = (_Float16)v[3];
  ((half4_t*)dst)[i] = h;
}

// ---------------- NT GEMM core: C[64x64 per wave] = A[M,K] * W[N,K]^T -------
__device__ __forceinline__ void gemm_acc_64x64(
    const _Float16* __restrict__ A, const _Float16* __restrict__ W, int K,
    int row0, int col0, int lr, int lg, float4_t acc[4][4]) {
  const _Float16* Ap = A + (size_t)(row0 + lr) * K + 8 * lg;
  const _Float16* Wp = W + (size_t)(col0 + lr) * K + 8 * lg;
  for (int k0 = 0; k0 < K; k0 += 32) {
    half8_t af[4], bf[4];
#pragma unroll
    for (int i = 0; i < 4; i++)
      af[i] = *(const half8_t*)(Ap + (size_t)(16 * i) * K + k0);
#pragma unroll
    for (int j = 0; j < 4; j++)
      bf[j] = *(const half8_t*)(Wp + (size_t)(16 * j) * K + k0);
#pragma unroll
    for (int i = 0; i < 4; i++)
#pragma unroll
      for (int j = 0; j < 4; j++)
        acc[i][j] = __builtin_amdgcn_mfma_f32_16x16x32_f16(af[i], bf[j], acc[i][j], 0, 0, 0);
  }
}

// ---------------- fused QKV + MLP1 projections ----------------
__global__ __launch_bounds__(256) void proj_kernel(
    const _Float16* __restrict__ xh,
    const _Float16* __restrict__ wqh, const _Float16* __restrict__ wkh,
    const _Float16* __restrict__ wvh, const _Float16* __restrict__ wm1h,
    const float* __restrict__ bq, const float* __restrict__ bk,
    const float* __restrict__ bv, const float* __restrict__ bm1,
    _Float16* __restrict__ Qh, _Float16* __restrict__ Kh,
    _Float16* __restrict__ Vh, _Float16* __restrict__ Hm) {
  int z = blockIdx.z;
  const _Float16* W; const float* bias; _Float16* out; int N; bool act = false;
  if (z == 0)      { W = wqh;  bias = bq;  out = Qh; N = 1024; }
  else if (z == 1) { W = wkh;  bias = bk;  out = Kh; N = 1024; }
  else if (z == 2) { W = wvh;  bias = bv;  out = Vh; N = 1024; }
  else             { W = wm1h; bias = bm1; out = Hm; N = 512; act = true; }
  int colB = blockIdx.y * 128;
  if (colB >= N) return;
  int wave = threadIdx.x >> 6, lane = threadIdx.x & 63;
  int lr = lane & 15, lg = lane >> 4;
  int row0 = blockIdx.x * 128 + (wave >> 1) * 64;
  int col0 = colB + (wave & 1) * 64;
  float4_t acc[4][4];
#pragma unroll
  for (int i = 0; i < 4; i++)
#pragma unroll
    for (int j = 0; j < 4; j++) acc[i][j] = (float4_t){0.f, 0.f, 0.f, 0.f};
  gemm_acc_64x64(xh, W, 1024, row0, col0, lr, lg, acc);
#pragma unroll
  for (int j = 0; j < 4; j++) {
    int col = col0 + 16 * j + lr;
    float bb = bias[col];
#pragma unroll
    for (int i = 0; i < 4; i++) {
#pragma unroll
      for (int r = 0; r < 4; r++) {
        int row = row0 + 16 * i + 4 * lg + r;
        float v = acc[i][j][r] + bb;
        if (act) v = 0.5f * v * (1.0f + erff(v * 0.70710678118f));
        out[(size_t)row * N + col] = (_Float16)v;
      }
    }
  }
}

// ---------------- output projection (writes f32 to d_out) ----------------
__global__ __launch_bounds__(256) void outproj_kernel(
    const _Float16* __restrict__ ctxh, const _Float16* __restrict__ woh,
    const float* __restrict__ bo, float* __restrict__ out) {
  int wave = threadIdx.x >> 6, lane = threadIdx.x & 63;
  int lr = lane & 15, lg = lane >> 4;
  int row0 = blockIdx.x * 128 + (wave >> 1) * 64;
  int col0 = blockIdx.y * 128 + (wave & 1) * 64;
  float4_t acc[4][4];
#pragma unroll
  for (int i = 0; i < 4; i++)
#pragma unroll
    for (int j = 0; j < 4; j++) acc[i][j] = (float4_t){0.f, 0.f, 0.f, 0.f};
  gemm_acc_64x64(ctxh, woh, 1024, row0, col0, lr, lg, acc);
#pragma unroll
  for (int j = 0; j < 4; j++) {
    int col = col0 + 16 * j + lr;
    float bb = bo[col];
#pragma unroll
    for (int i = 0; i < 4; i++) {
#pragma unroll
      for (int r = 0; r < 4; r++) {
        int row = row0 + 16 * i + 4 * lg + r;
        out[(size_t)row * 1024 + col] = acc[i][j][r] + bb;
      }
    }
  }
}

// ---------------- mechanism logits: Hm[4096,512] . Wm2[512] + bm2 ----------
__global__ __launch_bounds__(256) void mech_logits_kernel(
    const _Float16* __restrict__ Hm, const float* __restrict__ Wm2,
    const float* __restrict__ bm2, float* __restrict__ logits) {
  int wave = threadIdx.x >> 6, lane = threadIdx.x & 63;
  int row = blockIdx.x * 4 + wave;
  half8_t hv = *(const half8_t*)(Hm + (size_t)row * 512 + lane * 8);
  float4_t w0 = *(const float4_t*)(Wm2 + lane * 8);
  float4_t w1 = *(const float4_t*)(Wm2 + lane * 8 + 4);
  float s = 0.f;
#pragma unroll
  for (int j = 0; j < 4; j++) s += (float)hv[j] * w0[j];
#pragma unroll
  for (int j = 0; j < 4; j++) s += (float)hv[4 + j] * w1[j];
#pragma unroll
  for (int m = 32; m >= 1; m >>= 1) s += __shfl_xor(s, m, 64);
  if (lane == 0) logits[row] = s + bm2[0];
}

// ---------------- per-batch softmax over 2048 logits ----------------
__global__ __launch_bounds__(256) void mech_softmax_kernel(
    const float* __restrict__ logits, float* __restrict__ mech_ws,
    float* __restrict__ mech_out) {
  int b = blockIdx.x;
  int t = threadIdx.x;
  int wave = t >> 6, lane = t & 63;
  __shared__ float redmax[4];
  __shared__ float redsum[4];
  const float4_t* L4 = (const float4_t*)(logits + (size_t)b * 2048);
  float4_t v0 = L4[2 * t], v1 = L4[2 * t + 1];
  float mx = fmaxf(fmaxf(fmaxf(v0[0], v0[1]), fmaxf(v0[2], v0[3])),
                   fmaxf(fmaxf(v1[0], v1[1]), fmaxf(v1[2], v1[3])));
#pragma unroll
  for (int m = 32; m >= 1; m >>= 1) mx = fmaxf(mx, __shfl_xor(mx, m, 64));
  if (lane == 0) redmax[wave] = mx;
  __syncthreads();
  mx = fmaxf(fmaxf(redmax[0], redmax[1]), fmaxf(redmax[2], redmax[3]));
  float e[8];
  float s = 0.f;
#pragma unroll
  for (int j = 0; j < 4; j++) { e[j] = __expf(v0[j] - mx); s += e[j]; }
#pragma unroll
  for (int j = 0; j < 4; j++) { e[4 + j] = __expf(v1[j] - mx); s += e[4 + j]; }
#pragma unroll
  for (int m = 32; m >= 1; m >>= 1) s += __shfl_xor(s, m, 64);
  if (lane == 0) redsum[wave] = s;
  __syncthreads();
  s = redsum[0] + redsum[1] + redsum[2] + redsum[3];
  float inv = 1.0f / s;
  size_t base = (size_t)b * 2048 + (size_t)t * 8;
#pragma unroll
  for (int j = 0; j < 8; j++) {
    float val = e[j] * inv;
    mech_ws[base + j] = val;
    mech_out[base + j] = val;
  }
}

// ---------------- V transpose: Vh[4096,1024] -> VT[B*H][64][2048] ----------
__global__ __launch_bounds__(256) void vtrans_kernel(const _Float16* __restrict__ Vh,
                                                     _Float16* __restrict__ VT) {
  int bh = blockIdx.y;
  int b = bh >> 4, h = bh & 15;
  int k0 = blockIdx.x * 64;
  __shared__ _Float16 tile[64][65];
  int t = threadIdx.x;
#pragma unroll
  for (int rep = 0; rep < 16; rep++) {
    int idx = rep * 256 + t;
    int k = idx >> 6, d = idx & 63;
    tile[d][k] = Vh[(size_t)(b * 2048 + k0 + k) * 1024 + h * 64 + d];
  }
  __syncthreads();
#pragma unroll
  for (int rep = 0; rep < 16; rep++) {
    int idx = rep * 256 + t;
    int d = idx >> 6, k = idx & 63;
    VT[((size_t)bh * 64 + d) * 2048 + k0 + k] = tile[d][k];
  }
}

// ---------------- flash attention with mechanism bias ----------------
// swapped QK^T: s = mfma(K-frag, Q-frag) -> lane holds P[q=lane&15][k=4*lg+r],
// which IS the A-fragment of mfma_f32_16x16x16f16 for the PV step.
// Round 4: K/V tiles staged in LDS (double-buffered, T14 split: global loads
// issued before compute, ds_write after, one barrier/tile). Pads = 70 halves
// (140 B) -> <=2-way bank aliasing on all ds_read/ds_write patterns (free).
__global__ __launch_bounds__(256) void attn_kernel(
    const _Float16* __restrict__ Qh, const _Float16* __restrict__ Kh,
    const _Float16* __restrict__ VT, const float* __restrict__ mech,
    const int* __restrict__ mask, _Float16* __restrict__ ctxh) {
  __shared__ _Float16 Kl[2][64][70];
  __shared__ _Float16 Vl[2][64][70];
  __shared__ _Float16 bias_h[2048];
  int bh = blockIdx.y;
  int b = bh >> 4, h = bh & 15;
  int tid = threadIdx.x;
  for (int i = tid; i < 2048; i += 256) {
    float bv_ = 2.0f * mech[(size_t)b * 2048 + i] +
                (mask[(size_t)b * 2048 + i] != 0 ? 0.0f : -30000.0f);
    bias_h[i] = (_Float16)bv_;
  }
  const _Float16* Kg = Kh + ((size_t)b * 2048) * 1024 + h * 64;  // +k*1024+d
  const _Float16* Vg = VT + ((size_t)bh * 64) * 2048;            // +d*2048+k
  // staging map: 512 16B-chunks = 64 rows x 8; thread t does chunks t, t+256
  int rr0 = tid >> 3;            // rows 0..31
  int rr1 = rr0 + 32;            // rows 32..63
  int cc0 = (tid & 7) * 8;       // halves within 128B row
  // ---- stage tile 0 into buffer 0 ----
  {
    half8_t ka = *(const half8_t*)(Kg + (size_t)rr0 * 1024 + cc0);
    half8_t kb = *(const half8_t*)(Kg + (size_t)rr1 * 1024 + cc0);
    half8_t va = *(const half8_t*)(Vg + (size_t)rr0 * 2048 + cc0);
    half8_t vb = *(const half8_t*)(Vg + (size_t)rr1 * 2048 + cc0);
    *(half8_t*)&Kl[0][rr0][cc0] = ka;
    *(half8_t*)&Kl[0][rr1][cc0] = kb;
    *(half8_t*)&Vl[0][rr0][cc0] = va;
    *(half8_t*)&Vl[0][rr1][cc0] = vb;
  }
  __syncthreads();

  int wave = tid >> 6, lane = tid & 63;
  int lr = lane & 15, lg = lane >> 4;
  int q0 = blockIdx.x * 64 + wave * 16;
  const _Float16* Qp = Qh + (size_t)(b * 2048 + q0 + lr) * 1024 + h * 64 + 8 * lg;
  half8_t qf0 = *(const half8_t*)Qp;
  half8_t qf1 = *(const half8_t*)(Qp + 32);

  float m_run = -1e30f;   // per-lane running max (q = lr)
  float l_run = 0.0f;     // per-lane PARTIAL sum
  float4_t cacc[4];
#pragma unroll
  for (int dd = 0; dd < 4; dd++) cacc[dd] = (float4_t){0.f, 0.f, 0.f, 0.f};

  int cur = 0;
  for (int k0 = 0; k0 < 2048; k0 += 64) {
    // ---- T14: issue next tile's global loads now, write to LDS later ----
    half8_t ka, kb, va, vb;
    const bool hn = (k0 + 64) < 2048;
    if (hn) {
      int kn = k0 + 64;
      ka = *(const half8_t*)(Kg + (size_t)(kn + rr0) * 1024 + cc0);
      kb = *(const half8_t*)(Kg + (size_t)(kn + rr1) * 1024 + cc0);
      va = *(const half8_t*)(Vg + (size_t)rr0 * 2048 + kn + cc0);
      vb = *(const half8_t*)(Vg + (size_t)rr1 * 2048 + kn + cc0);
    }
    // ---- compute current tile from LDS buffer `cur` ----
    const _Float16* Kb = &Kl[cur][0][0];
    const _Float16* Vb = &Vl[cur][0][0];
    float4_t s[4];
#pragma unroll
    for (int t = 0; t < 4; t++) {
      half8_t kf0 = *(const half8_t*)(Kb + (16 * t + lr) * 70 + 8 * lg);
      half8_t kf1 = *(const half8_t*)(Kb + (16 * t + lr) * 70 + 8 * lg + 32);
      float4_t z = (float4_t){0.f, 0.f, 0.f, 0.f};
      z = __builtin_amdgcn_mfma_f32_16x16x32_f16(kf0, qf0, z, 0, 0, 0);
      z = __builtin_amdgcn_mfma_f32_16x16x32_f16(kf1, qf1, z, 0, 0, 0);
      s[t] = z;
    }
#pragma unroll
    for (int t = 0; t < 4; t++) {
      half4_t b4 = *(const half4_t*)&bias_h[k0 + 16 * t + 4 * lg];
#pragma unroll
      for (int r = 0; r < 4; r++)
        s[t][r] = s[t][r] * 0.125f + (float)b4[r];
    }
    float tm0 = fmaxf(fmaxf(s[0][0], s[0][1]), fmaxf(s[0][2], s[0][3]));
    float tm1 = fmaxf(fmaxf(s[1][0], s[1][1]), fmaxf(s[1][2], s[1][3]));
    float tm2 = fmaxf(fmaxf(s[2][0], s[2][1]), fmaxf(s[2][2], s[2][3]));
    float tm3 = fmaxf(fmaxf(s[3][0], s[3][1]), fmaxf(s[3][2], s[3][3]));
    float tm = fmaxf(fmaxf(tm0, tm1), fmaxf(tm2, tm3));
    tm = fmaxf(tm, __shfl_xor(tm, 16, 64));
    tm = fmaxf(tm, __shfl_xor(tm, 32, 64));
    if (__any(tm > m_run + 8.0f)) {   // defer-max: rare rescale
      float m_new = fmaxf(m_run, tm);
      float alpha = __expf(m_run - m_new);
      l_run *= alpha;
      m_run = m_new;
      int rbase = 4 * lg;
      float a0 = __shfl(alpha, rbase + 0, 64);
      float a1 = __shfl(alpha, rbase + 1, 64);
      float a2 = __shfl(alpha, rbase + 2, 64);
      float a3 = __shfl(alpha, rbase + 3, 64);
#pragma unroll
      for (int dd = 0; dd < 4; dd++) {
        cacc[dd][0] *= a0; cacc[dd][1] *= a1;
        cacc[dd][2] *= a2; cacc[dd][3] *= a3;
      }
    }
    half4_t pa[4];
#pragma unroll
    for (int t = 0; t < 4; t++) {
#pragma unroll
      for (int r = 0; r < 4; r++) {
        float p = __expf(s[t][r] - m_run);
        l_run += p;
        pa[t][r] = (_Float16)p;
      }
    }
#pragma unroll
    for (int dd = 0; dd < 4; dd++) {
#pragma unroll
      for (int t = 0; t < 4; t++) {
        half4_t vf = *(const half4_t*)(Vb + (16 * dd + lr) * 70 + 16 * t + 4 * lg);
        cacc[dd] = __builtin_amdgcn_mfma_f32_16x16x16f16(pa[t], vf, cacc[dd], 0, 0, 0);
      }
    }
    // ---- write staged next tile, single barrier per tile ----
    if (hn) {
      *(half8_t*)&Kl[cur ^ 1][rr0][cc0] = ka;
      *(half8_t*)&Kl[cur ^ 1][rr1][cc0] = kb;
      *(half8_t*)&Vl[cur ^ 1][rr0][cc0] = va;
      *(half8_t*)&Vl[cur ^ 1][rr1][cc0] = vb;
    }
    __syncthreads();
    cur ^= 1;
  }
  // ---- finalize ----
  l_run += __shfl_xor(l_run, 16, 64);
  l_run += __shfl_xor(l_run, 32, 64);
  float linv = 1.0f / l_run;
  int rbase = 4 * lg;
  float i0 = __shfl(linv, rbase + 0, 64);
  float i1 = __shfl(linv, rbase + 1, 64);
  float i2 = __shfl(linv, rbase + 2, 64);
  float i3 = __shfl(linv, rbase + 3, 64);
  float invs[4] = {i0, i1, i2, i3};
#pragma unroll
  for (int dd = 0; dd < 4; dd++) {
#pragma unroll
    for (int r = 0; r < 4; r++) {
      size_t idx = (size_t)(b * 2048 + q0 + rbase + r) * 1024 + h * 64 + 16 * dd + lr;
      ctxh[idx] = (_Float16)(cacc[dd][r] * invs[r]);
    }
  }
}

extern "C" void kernel_launch(void* const* d_in, const int* in_sizes, int n_in,
                              void* d_out, int out_size, void* d_ws, size_t ws_size,
                              hipStream_t stream) {
  const float* x    = (const float*)d_in[0];
  const int*   mask = (const int*)d_in[1];
  const float* Wq   = (const float*)d_in[2];
  const float* bq   = (const float*)d_in[3];
  const float* Wk   = (const float*)d_in[4];
  const float* bk   = (const float*)d_in[5];
  const float* Wv   = (const float*)d_in[6];
  const float* bv   = (const float*)d_in[7];
  const float* Wo   = (const float*)d_in[8];
  const float* bo   = (const float*)d_in[9];
  const float* Wm1  = (const float*)d_in[10];
  const float* bm1  = (const float*)d_in[11];
  const float* Wm2  = (const float*)d_in[12];
  const float* bm2  = (const float*)d_in[13];
  float* outp = (float*)d_out;
  float* mech_out = outp + (size_t)MTOT * DMODEL;

  char* ws = (char*)d_ws;
  _Float16* xh   = (_Float16*)(ws + 0);
  _Float16* wqh  = (_Float16*)(ws + 8388608);
  _Float16* wkh  = (_Float16*)(ws + 10485760);
  _Float16* wvh  = (_Float16*)(ws + 12582912);
  _Float16* woh  = (_Float16*)(ws + 14680064);
  _Float16* wm1h = (_Float16*)(ws + 16777216);
  _Float16* Qh   = (_Float16*)(ws + 17825792);
  _Float16* Kh   = (_Float16*)(ws + 26214400);
  _Float16* Vh   = (_Float16*)(ws + 34603008);
  _Float16* VT   = (_Float16*)(ws + 42991616);
  _Float16* ctxh = (_Float16*)(ws + 51380224);
  _Float16* Hm   = (_Float16*)(ws + 59768832);
  float* logits  = (float*)(ws + 63963136);
  float* mech_ws = (float*)(ws + 63979520);

  hipLaunchKernelGGL(cvt_all_kernel, dim3(4608, 2), dim3(256), 0, stream,
                     x, Wq, Wk, Wv, Wo, Wm1, xh, wqh, wkh, wvh, woh, wm1h);

  hipLaunchKernelGGL(proj_kernel, dim3(32, 8, 4), dim3(256), 0, stream,
                     xh, wqh, wkh, wvh, wm1h, bq, bk, bv, bm1, Qh, Kh, Vh, Hm);

  hipLaunchKernelGGL(mech_logits_kernel, dim3(1024), dim3(256), 0, stream,
                     Hm, Wm2, bm2, logits);
  hipLaunchKernelGGL(mech_softmax_kernel, dim3(2), dim3(256), 0, stream,
                     logits, mech_ws, mech_out);

  hipLaunchKernelGGL(vtrans_kernel, dim3(32, 32), dim3(256), 0, stream, Vh, VT);

  hipLaunchKernelGGL(attn_kernel, dim3(32, 32), dim3(256), 0, stream,
                     Qh, Kh, VT, mech_ws, mask, ctxh);

  hipLaunchKernelGGL(outproj_kernel, dim3(32, 8), dim3(256), 0, stream,
                     ctxh, woh, bo, outp);
}

// Round 5
// 442.605 us; speedup vs baseline: 1.4322x; 1.4322x over previous
//
#include <hip/hip_runtime.h>
#include <hip/hip_fp16.h>
#include <math.h>

typedef _Float16 half4_t __attribute__((ext_vector_type(4)));
typedef _Float16 half8_t __attribute__((ext_vector_type(8)));
typedef float float4_t __attribute__((ext_vector_type(4)));

static constexpr int DMODEL = 1024;
static constexpr int SLEN   = 2048;
static constexpr int NHEADS = 16;
static constexpr int MTOT   = 4096;   // B * S

// ---------------- fused f32 -> f16 convert (x + all 5 weights) ----------------
__global__ __launch_bounds__(256) void cvt_all_kernel(
    const float* __restrict__ x,
    const float* __restrict__ Wq, const float* __restrict__ Wk,
    const float* __restrict__ Wv, const float* __restrict__ Wo,
    const float* __restrict__ Wm1,
    _Float16* __restrict__ xh, _Float16* __restrict__ wqh,
    _Float16* __restrict__ wkh, _Float16* __restrict__ wvh,
    _Float16* __restrict__ woh, _Float16* __restrict__ wm1h) {
  int bx = blockIdx.x;
  const float* src; _Float16* dst; int lb;
  if (blockIdx.y == 0) {
    if (bx >= 4096) return;
    src = x; dst = xh; lb = bx;
  } else {
    if (bx < 1024)      { src = Wq;  dst = wqh;  lb = bx; }
    else if (bx < 2048) { src = Wk;  dst = wkh;  lb = bx - 1024; }
    else if (bx < 3072) { src = Wv;  dst = wvh;  lb = bx - 2048; }
    else if (bx < 4096) { src = Wo;  dst = woh;  lb = bx - 3072; }
    else                { src = Wm1; dst = wm1h; lb = bx - 4096; }
  }
  int i = lb * 256 + threadIdx.x;
  float4_t v = ((const float4_t*)src)[i];
  half4_t h;
  h[0] = (_Float16)v[0]; h[1] = (_Float16)v[1];
  h[2] = (_Float16)v[2]; h[3] = (_Float16)v[3];
  ((half4_t*)dst)[i] = h;
}

// ---------------- NT GEMM core: C[64x64 per wave] = A[M,K] * W[N,K]^T -------
// A/B frags share the per-lane k-map -> k-permutation invariant.
// D layout (HW-verified): col=lane&15, row=4*(lane>>4)+reg.
__device__ __forceinline__ void gemm_acc_64x64(
    const _Float16* __restrict__ A, const _Float16* __restrict__ W, int K,
    int row0, int col0, int lr, int lg, float4_t acc[4][4]) {
  const _Float16* Ap = A + (size_t)(row0 + lr) * K + 8 * lg;
  const _Float16* Wp = W + (size_t)(col0 + lr) * K + 8 * lg;
  for (int k0 = 0; k0 < K; k0 += 32) {
    half8_t af[4], bf[4];
#pragma unroll
    for (int i = 0; i < 4; i++)
      af[i] = *(const half8_t*)(Ap + (size_t)(16 * i) * K + k0);
#pragma unroll
    for (int j = 0; j < 4; j++)
      bf[j] = *(const half8_t*)(Wp + (size_t)(16 * j) * K + k0);
#pragma unroll
    for (int i = 0; i < 4; i++)
#pragma unroll
      for (int j = 0; j < 4; j++)
        acc[i][j] = __builtin_amdgcn_mfma_f32_16x16x32_f16(af[i], bf[j], acc[i][j], 0, 0, 0);
  }
}

// ---------------- fused QKV + MLP1 projections ----------------
__global__ __launch_bounds__(256, 2) void proj_kernel(
    const _Float16* __restrict__ xh,
    const _Float16* __restrict__ wqh, const _Float16* __restrict__ wkh,
    const _Float16* __restrict__ wvh, const _Float16* __restrict__ wm1h,
    const float* __restrict__ bq, const float* __restrict__ bk,
    const float* __restrict__ bv, const float* __restrict__ bm1,
    _Float16* __restrict__ Qh, _Float16* __restrict__ Kh,
    _Float16* __restrict__ Vh, _Float16* __restrict__ Hm) {
  int z = blockIdx.z;
  const _Float16* W; const float* bias; _Float16* out; int N; bool act = false;
  if (z == 0)      { W = wqh;  bias = bq;  out = Qh; N = 1024; }
  else if (z == 1) { W = wkh;  bias = bk;  out = Kh; N = 1024; }
  else if (z == 2) { W = wvh;  bias = bv;  out = Vh; N = 1024; }
  else             { W = wm1h; bias = bm1; out = Hm; N = 512; act = true; }
  int colB = blockIdx.y * 128;
  if (colB >= N) return;
  int wave = threadIdx.x >> 6, lane = threadIdx.x & 63;
  int lr = lane & 15, lg = lane >> 4;
  int row0 = blockIdx.x * 128 + (wave >> 1) * 64;
  int col0 = colB + (wave & 1) * 64;
  float4_t acc[4][4];
#pragma unroll
  for (int i = 0; i < 4; i++)
#pragma unroll
    for (int j = 0; j < 4; j++) acc[i][j] = (float4_t){0.f, 0.f, 0.f, 0.f};
  gemm_acc_64x64(xh, W, 1024, row0, col0, lr, lg, acc);
#pragma unroll
  for (int j = 0; j < 4; j++) {
    int col = col0 + 16 * j + lr;
    float bb = bias[col];
#pragma unroll
    for (int i = 0; i < 4; i++) {
#pragma unroll
      for (int r = 0; r < 4; r++) {
        int row = row0 + 16 * i + 4 * lg + r;
        float v = acc[i][j][r] + bb;
        if (act) v = 0.5f * v * (1.0f + erff(v * 0.70710678118f));
        out[(size_t)row * N + col] = (_Float16)v;
      }
    }
  }
}

// ---------------- output projection (writes f32 to d_out) ----------------
__global__ __launch_bounds__(256, 2) void outproj_kernel(
    const _Float16* __restrict__ ctxh, const _Float16* __restrict__ woh,
    const float* __restrict__ bo, float* __restrict__ out) {
  int wave = threadIdx.x >> 6, lane = threadIdx.x & 63;
  int lr = lane & 15, lg = lane >> 4;
  int row0 = blockIdx.x * 128 + (wave >> 1) * 64;
  int col0 = blockIdx.y * 128 + (wave & 1) * 64;
  float4_t acc[4][4];
#pragma unroll
  for (int i = 0; i < 4; i++)
#pragma unroll
    for (int j = 0; j < 4; j++) acc[i][j] = (float4_t){0.f, 0.f, 0.f, 0.f};
  gemm_acc_64x64(ctxh, woh, 1024, row0, col0, lr, lg, acc);
#pragma unroll
  for (int j = 0; j < 4; j++) {
    int col = col0 + 16 * j + lr;
    float bb = bo[col];
#pragma unroll
    for (int i = 0; i < 4; i++) {
#pragma unroll
      for (int r = 0; r < 4; r++) {
        int row = row0 + 16 * i + 4 * lg + r;
        out[(size_t)row * 1024 + col] = acc[i][j][r] + bb;
      }
    }
  }
}

// ---------------- mechanism logits: Hm[4096,512] . Wm2[512] + bm2 ----------
__global__ __launch_bounds__(256) void mech_logits_kernel(
    const _Float16* __restrict__ Hm, const float* __restrict__ Wm2,
    const float* __restrict__ bm2, float* __restrict__ logits) {
  int wave = threadIdx.x >> 6, lane = threadIdx.x & 63;
  int row = blockIdx.x * 4 + wave;
  half8_t hv = *(const half8_t*)(Hm + (size_t)row * 512 + lane * 8);
  float4_t w0 = *(const float4_t*)(Wm2 + lane * 8);
  float4_t w1 = *(const float4_t*)(Wm2 + lane * 8 + 4);
  float s = 0.f;
#pragma unroll
  for (int j = 0; j < 4; j++) s += (float)hv[j] * w0[j];
#pragma unroll
  for (int j = 0; j < 4; j++) s += (float)hv[4 + j] * w1[j];
#pragma unroll
  for (int m = 32; m >= 1; m >>= 1) s += __shfl_xor(s, m, 64);
  if (lane == 0) logits[row] = s + bm2[0];
}

// ---------------- per-batch softmax over 2048 logits ----------------
__global__ __launch_bounds__(256) void mech_softmax_kernel(
    const float* __restrict__ logits, float* __restrict__ mech_ws,
    float* __restrict__ mech_out) {
  int b = blockIdx.x;
  int t = threadIdx.x;
  int wave = t >> 6, lane = t & 63;
  __shared__ float redmax[4];
  __shared__ float redsum[4];
  const float4_t* L4 = (const float4_t*)(logits + (size_t)b * 2048);
  float4_t v0 = L4[2 * t], v1 = L4[2 * t + 1];
  float mx = fmaxf(fmaxf(fmaxf(v0[0], v0[1]), fmaxf(v0[2], v0[3])),
                   fmaxf(fmaxf(v1[0], v1[1]), fmaxf(v1[2], v1[3])));
#pragma unroll
  for (int m = 32; m >= 1; m >>= 1) mx = fmaxf(mx, __shfl_xor(mx, m, 64));
  if (lane == 0) redmax[wave] = mx;
  __syncthreads();
  mx = fmaxf(fmaxf(redmax[0], redmax[1]), fmaxf(redmax[2], redmax[3]));
  float e[8];
  float s = 0.f;
#pragma unroll
  for (int j = 0; j < 4; j++) { e[j] = __expf(v0[j] - mx); s += e[j]; }
#pragma unroll
  for (int j = 0; j < 4; j++) { e[4 + j] = __expf(v1[j] - mx); s += e[4 + j]; }
#pragma unroll
  for (int m = 32; m >= 1; m >>= 1) s += __shfl_xor(s, m, 64);
  if (lane == 0) redsum[wave] = s;
  __syncthreads();
  s = redsum[0] + redsum[1] + redsum[2] + redsum[3];
  float inv = 1.0f / s;
  size_t base = (size_t)b * 2048 + (size_t)t * 8;
#pragma unroll
  for (int j = 0; j < 8; j++) {
    float val = e[j] * inv;
    mech_ws[base + j] = val;
    mech_out[base + j] = val;
  }
}

// ---------------- V transpose: Vh[4096,1024] -> VT[B*H][64][2048] ----------
__global__ __launch_bounds__(256) void vtrans_kernel(const _Float16* __restrict__ Vh,
                                                     _Float16* __restrict__ VT) {
  int bh = blockIdx.y;
  int b = bh >> 4, h = bh & 15;
  int k0 = blockIdx.x * 64;
  __shared__ _Float16 tile[64][65];
  int t = threadIdx.x;
#pragma unroll
  for (int rep = 0; rep < 16; rep++) {
    int idx = rep * 256 + t;
    int k = idx >> 6, d = idx & 63;
    tile[d][k] = Vh[(size_t)(b * 2048 + k0 + k) * 1024 + h * 64 + d];
  }
  __syncthreads();
#pragma unroll
  for (int rep = 0; rep < 16; rep++) {
    int idx = rep * 256 + t;
    int d = idx >> 6, k = idx & 63;
    VT[((size_t)bh * 64 + d) * 2048 + k0 + k] = tile[d][k];
  }
}

// ---------------- flash attention with mechanism bias ----------------
// swapped QK^T: s = mfma(K-frag, Q-frag) -> lane holds P[q=lr][k=4*lg+r] per
// group; that IS the A-fragment of mfma_f32_16x16x16f16 for the PV step.
// Round 5: latency fix. Each wave owns 32 q-rows (2 groups sharing K/V frags),
// ALL 24 K/V loads per 64-key tile batched into registers up front (one wait),
// __launch_bounds__(256,2) lifts the VGPR cap so the compiler can hold them.
// No K/V LDS staging (L1/L2-resident), no per-tile barrier.
__global__ __launch_bounds__(256, 2) void attn_kernel(
    const _Float16* __restrict__ Qh, const _Float16* __restrict__ Kh,
    const _Float16* __restrict__ VT, const float* __restrict__ mech,
    const int* __restrict__ mask, _Float16* __restrict__ ctxh) {
  __shared__ float bias_s[2048];
  int bh = blockIdx.y;
  int b = bh >> 4, h = bh & 15;
  for (int i = threadIdx.x; i < 2048; i += 256)
    bias_s[i] = 2.0f * mech[(size_t)b * 2048 + i] +
                (mask[(size_t)b * 2048 + i] != 0 ? 0.0f : -1e30f);
  __syncthreads();
  int wave = threadIdx.x >> 6, lane = threadIdx.x & 63;
  int lr = lane & 15, lg = lane >> 4;
  int q0 = blockIdx.x * 128 + wave * 32;   // 32 q-rows per wave

  const _Float16* Qbase = Qh + (size_t)(b * 2048 + q0 + lr) * 1024 + h * 64 + 8 * lg;
  half8_t qf[2][2];
  qf[0][0] = *(const half8_t*)(Qbase);
  qf[0][1] = *(const half8_t*)(Qbase + 32);
  qf[1][0] = *(const half8_t*)(Qbase + (size_t)16 * 1024);
  qf[1][1] = *(const half8_t*)(Qbase + (size_t)16 * 1024 + 32);
  const _Float16* Kp = Kh + (size_t)(b * 2048 + lr) * 1024 + h * 64 + 8 * lg;
  const _Float16* Vp = VT + ((size_t)bh * 64 + lr) * 2048 + 4 * lg;

  float m0 = -1e30f, m1 = -1e30f;   // per-lane running max (q = lr, per group)
  float l0 = 0.0f, l1 = 0.0f;       // per-lane PARTIAL exp-sums
  float4_t cacc[2][4];
#pragma unroll
  for (int g = 0; g < 2; g++)
#pragma unroll
    for (int dd = 0; dd < 4; dd++) cacc[g][dd] = (float4_t){0.f, 0.f, 0.f, 0.f};

  for (int k0 = 0; k0 < 2048; k0 += 64) {
    // ---- batched loads: all K and V fragments for this 64-key tile ----
    half8_t kf[4][2];
#pragma unroll
    for (int t = 0; t < 4; t++) {
      const _Float16* kp = Kp + (size_t)(k0 + 16 * t) * 1024;
      kf[t][0] = *(const half8_t*)kp;
      kf[t][1] = *(const half8_t*)(kp + 32);
    }
    half4_t vf[4][4];   // [dd][t]
#pragma unroll
    for (int dd = 0; dd < 4; dd++)
#pragma unroll
      for (int t = 0; t < 4; t++)
        vf[dd][t] = *(const half4_t*)(Vp + (size_t)(16 * dd) * 2048 + k0 + 16 * t);
    float4_t bias4[4];
#pragma unroll
    for (int t = 0; t < 4; t++)
      bias4[t] = *(const float4_t*)&bias_s[k0 + 16 * t + 4 * lg];
    // ---- QK^T for both q-groups (K frags reused) ----
    float4_t s0[4], s1[4];
#pragma unroll
    for (int t = 0; t < 4; t++) {
      float4_t z = (float4_t){0.f, 0.f, 0.f, 0.f};
      z = __builtin_amdgcn_mfma_f32_16x16x32_f16(kf[t][0], qf[0][0], z, 0, 0, 0);
      z = __builtin_amdgcn_mfma_f32_16x16x32_f16(kf[t][1], qf[0][1], z, 0, 0, 0);
      s0[t] = z;
      float4_t w = (float4_t){0.f, 0.f, 0.f, 0.f};
      w = __builtin_amdgcn_mfma_f32_16x16x32_f16(kf[t][0], qf[1][0], w, 0, 0, 0);
      w = __builtin_amdgcn_mfma_f32_16x16x32_f16(kf[t][1], qf[1][1], w, 0, 0, 0);
      s1[t] = w;
    }
    // ---- scores = s/8 + bias ----
#pragma unroll
    for (int t = 0; t < 4; t++)
#pragma unroll
      for (int r = 0; r < 4; r++) {
        s0[t][r] = s0[t][r] * 0.125f + bias4[t][r];
        s1[t][r] = s1[t][r] * 0.125f + bias4[t][r];
      }
    // ---- per-group tile max (2 shuffles each) ----
    float tm0 = s0[0][0], tm1 = s1[0][0];
#pragma unroll
    for (int t = 0; t < 4; t++)
#pragma unroll
      for (int r = 0; r < 4; r++) {
        tm0 = fmaxf(tm0, s0[t][r]);
        tm1 = fmaxf(tm1, s1[t][r]);
      }
    tm0 = fmaxf(tm0, __shfl_xor(tm0, 16, 64));
    tm0 = fmaxf(tm0, __shfl_xor(tm0, 32, 64));
    tm1 = fmaxf(tm1, __shfl_xor(tm1, 16, 64));
    tm1 = fmaxf(tm1, __shfl_xor(tm1, 32, 64));
    // ---- defer-max: rare rescale ----
    if (__any((tm0 > m0 + 8.0f) || (tm1 > m1 + 8.0f))) {
      float mn0 = fmaxf(m0, tm0), mn1 = fmaxf(m1, tm1);
      float a0 = __expf(m0 - mn0), a1 = __expf(m1 - mn1);
      l0 *= a0; l1 *= a1;
      m0 = mn0; m1 = mn1;
      int rbase = 4 * lg;
#pragma unroll
      for (int r = 0; r < 4; r++) {
        float b0 = __shfl(a0, rbase + r, 64);
        float b1 = __shfl(a1, rbase + r, 64);
#pragma unroll
        for (int dd = 0; dd < 4; dd++) {
          cacc[0][dd][r] *= b0;
          cacc[1][dd][r] *= b1;
        }
      }
    }
    // ---- P = exp(sc - m), per-lane l accumulation, f16 pack ----
    half4_t pa0[4], pa1[4];
#pragma unroll
    for (int t = 0; t < 4; t++) {
#pragma unroll
      for (int r = 0; r < 4; r++) {
        float p0 = __expf(s0[t][r] - m0);
        float p1 = __expf(s1[t][r] - m1);
        l0 += p0; l1 += p1;
        pa0[t][r] = (_Float16)p0;
        pa1[t][r] = (_Float16)p1;
      }
    }
    // ---- PV for both groups (V frags reused) ----
#pragma unroll
    for (int dd = 0; dd < 4; dd++)
#pragma unroll
      for (int t = 0; t < 4; t++) {
        cacc[0][dd] = __builtin_amdgcn_mfma_f32_16x16x16f16(pa0[t], vf[dd][t], cacc[0][dd], 0, 0, 0);
        cacc[1][dd] = __builtin_amdgcn_mfma_f32_16x16x16f16(pa1[t], vf[dd][t], cacc[1][dd], 0, 0, 0);
      }
  }
  // ---- finalize both groups ----
  l0 += __shfl_xor(l0, 16, 64);
  l0 += __shfl_xor(l0, 32, 64);
  l1 += __shfl_xor(l1, 16, 64);
  l1 += __shfl_xor(l1, 32, 64);
  float li0 = 1.0f / l0, li1 = 1.0f / l1;
  int rbase = 4 * lg;
#pragma unroll
  for (int r = 0; r < 4; r++) {
    float i0 = __shfl(li0, rbase + r, 64);
    float i1 = __shfl(li1, rbase + r, 64);
#pragma unroll
    for (int dd = 0; dd < 4; dd++) {
      size_t idx0 = (size_t)(b * 2048 + q0 + rbase + r) * 1024 + h * 64 + 16 * dd + lr;
      size_t idx1 = (size_t)(b * 2048 + q0 + 16 + rbase + r) * 1024 + h * 64 + 16 * dd + lr;
      ctxh[idx0] = (_Float16)(cacc[0][dd][r] * i0);
      ctxh[idx1] = (_Float16)(cacc[1][dd][r] * i1);
    }
  }
}

extern "C" void kernel_launch(void* const* d_in, const int* in_sizes, int n_in,
                              void* d_out, int out_size, void* d_ws, size_t ws_size,
                              hipStream_t stream) {
  const float* x    = (const float*)d_in[0];
  const int*   mask = (const int*)d_in[1];
  const float* Wq   = (const float*)d_in[2];
  const float* bq   = (const float*)d_in[3];
  const float* Wk   = (const float*)d_in[4];
  const float* bk   = (const float*)d_in[5];
  const float* Wv   = (const float*)d_in[6];
  const float* bv   = (const float*)d_in[7];
  const float* Wo   = (const float*)d_in[8];
  const float* bo   = (const float*)d_in[9];
  const float* Wm1  = (const float*)d_in[10];
  const float* bm1  = (const float*)d_in[11];
  const float* Wm2  = (const float*)d_in[12];
  const float* bm2  = (const float*)d_in[13];
  float* outp = (float*)d_out;
  float* mech_out = outp + (size_t)MTOT * DMODEL;

  char* ws = (char*)d_ws;
  _Float16* xh   = (_Float16*)(ws + 0);
  _Float16* wqh  = (_Float16*)(ws + 8388608);
  _Float16* wkh  = (_Float16*)(ws + 10485760);
  _Float16* wvh  = (_Float16*)(ws + 12582912);
  _Float16* woh  = (_Float16*)(ws + 14680064);
  _Float16* wm1h = (_Float16*)(ws + 16777216);
  _Float16* Qh   = (_Float16*)(ws + 17825792);
  _Float16* Kh   = (_Float16*)(ws + 26214400);
  _Float16* Vh   = (_Float16*)(ws + 34603008);
  _Float16* VT   = (_Float16*)(ws + 42991616);
  _Float16* ctxh = (_Float16*)(ws + 51380224);
  _Float16* Hm   = (_Float16*)(ws + 59768832);
  float* logits  = (float*)(ws + 63963136);
  float* mech_ws = (float*)(ws + 63979520);

  hipLaunchKernelGGL(cvt_all_kernel, dim3(4608, 2), dim3(256), 0, stream,
                     x, Wq, Wk, Wv, Wo, Wm1, xh, wqh, wkh, wvh, woh, wm1h);

  hipLaunchKernelGGL(proj_kernel, dim3(32, 8, 4), dim3(256), 0, stream,
                     xh, wqh, wkh, wvh, wm1h, bq, bk, bv, bm1, Qh, Kh, Vh, Hm);

  hipLaunchKernelGGL(mech_logits_kernel, dim3(1024), dim3(256), 0, stream,
                     Hm, Wm2, bm2, logits);
  hipLaunchKernelGGL(mech_softmax_kernel, dim3(2), dim3(256), 0, stream,
                     logits, mech_ws, mech_out);

  hipLaunchKernelGGL(vtrans_kernel, dim3(32, 32), dim3(256), 0, stream, Vh, VT);

  hipLaunchKernelGGL(attn_kernel, dim3(16, 32), dim3(256), 0, stream,
                     Qh, Kh, VT, mech_ws, mask, ctxh);

  hipLaunchKernelGGL(outproj_kernel, dim3(32, 8), dim3(256), 0, stream,
                     ctxh, woh, bo, outp);
}

// Round 7
// 274.814 us; speedup vs baseline: 2.3066x; 1.6106x over previous
//
#include <hip/hip_runtime.h>
#include <hip/hip_fp16.h>
#include <math.h>

typedef _Float16 half4_t __attribute__((ext_vector_type(4)));
typedef _Float16 half8_t __attribute__((ext_vector_type(8)));
typedef float float4_t __attribute__((ext_vector_type(4)));

static constexpr int DMODEL = 1024;
static constexpr int SLEN   = 2048;
static constexpr int NHEADS = 16;
static constexpr int MTOT   = 4096;   // B * S

// ============================================================================
// Fragment-packed operand layout (transaction minimization):
//   P[rt][ks][lane][8] for a row-major [R][K] NT-GEMM operand:
//     element (row, col): rt=row/16, ks=col/32, lane=((col%32)/8)*16 + row%16,
//     j=col%8.  One wave fragment load = lane*16B contiguous (1KB, 8 lines)
//     instead of 16 rows x 2KB stride (16 lines).
// ============================================================================

// ---- f32 -> f16 convert + fragment-pack (x + all 5 weights) ----
__global__ __launch_bounds__(256) void pack_all_kernel(
    const float* __restrict__ x,
    const float* __restrict__ Wq, const float* __restrict__ Wk,
    const float* __restrict__ Wv, const float* __restrict__ Wo,
    const float* __restrict__ Wm1,
    _Float16* __restrict__ xP, _Float16* __restrict__ wqP,
    _Float16* __restrict__ wkP, _Float16* __restrict__ wvP,
    _Float16* __restrict__ woP, _Float16* __restrict__ wm1P) {
  int bx = blockIdx.x;
  const float* src; _Float16* dst; int lb;
  if (blockIdx.y == 0) {
    if (bx >= 2048) return;
    src = x; dst = xP; lb = bx;
  } else {
    if (bx < 512)       { src = Wq;  dst = wqP;  lb = bx; }
    else if (bx < 1024) { src = Wk;  dst = wkP;  lb = bx - 512; }
    else if (bx < 1536) { src = Wv;  dst = wvP;  lb = bx - 1024; }
    else if (bx < 2048) { src = Wo;  dst = woP;  lb = bx - 1536; }
    else                { src = Wm1; dst = wm1P; lb = bx - 2048; }
  }
  int c = lb * 256 + threadIdx.x;     // chunk id
  int lane = c & 63;
  int ks = (c >> 6) & 31;             // K = 1024 -> 32 k-steps
  int rt = c >> 11;
  int row = 16 * rt + (lane & 15);
  int col = 32 * ks + 8 * (lane >> 4);
  const float* sp = src + (size_t)row * 1024 + col;
  float4_t v0 = *(const float4_t*)sp;
  float4_t v1 = *(const float4_t*)(sp + 4);
  half8_t h;
  h[0] = (_Float16)v0[0]; h[1] = (_Float16)v0[1];
  h[2] = (_Float16)v0[2]; h[3] = (_Float16)v0[3];
  h[4] = (_Float16)v1[0]; h[5] = (_Float16)v1[1];
  h[6] = (_Float16)v1[2]; h[7] = (_Float16)v1[3];
  *(half8_t*)(dst + (size_t)c * 8) = h;
}

// ---- fused QKV + MLP1 projections (packed A, packed W) ----
__global__ __launch_bounds__(256, 2) void proj_kernel(
    const _Float16* __restrict__ xP,
    const _Float16* __restrict__ wqP, const _Float16* __restrict__ wkP,
    const _Float16* __restrict__ wvP, const _Float16* __restrict__ wm1P,
    const float* __restrict__ bq, const float* __restrict__ bk,
    const float* __restrict__ bv, const float* __restrict__ bm1,
    _Float16* __restrict__ Qh, _Float16* __restrict__ Kh,
    _Float16* __restrict__ Vh, _Float16* __restrict__ Hm) {
  int z = blockIdx.z;
  const _Float16* W; const float* bias; _Float16* out; int N; bool act = false;
  if (z == 0)      { W = wqP;  bias = bq;  out = Qh; N = 1024; }
  else if (z == 1) { W = wkP;  bias = bk;  out = Kh; N = 1024; }
  else if (z == 2) { W = wvP;  bias = bv;  out = Vh; N = 1024; }
  else             { W = wm1P; bias = bm1; out = Hm; N = 512; act = true; }
  int colB = blockIdx.y * 128;
  if (colB >= N) return;
  int wave = threadIdx.x >> 6, lane = threadIdx.x & 63;
  int lr = lane & 15, lg = lane >> 4;
  int row0 = blockIdx.x * 128 + (wave >> 1) * 64;
  int col0 = colB + (wave & 1) * 64;
  int rt0 = row0 >> 4, ct0 = col0 >> 4;
  float4_t acc[4][4];
#pragma unroll
  for (int i = 0; i < 4; i++)
#pragma unroll
    for (int j = 0; j < 4; j++) acc[i][j] = (float4_t){0.f, 0.f, 0.f, 0.f};
  for (int ks = 0; ks < 32; ks++) {
    half8_t af[4], bf[4];
#pragma unroll
    for (int i = 0; i < 4; i++)
      af[i] = *(const half8_t*)(xP + (((size_t)(rt0 + i) * 32 + ks) << 9) + (lane << 3));
#pragma unroll
    for (int j = 0; j < 4; j++)
      bf[j] = *(const half8_t*)(W + (((size_t)(ct0 + j) * 32 + ks) << 9) + (lane << 3));
#pragma unroll
    for (int i = 0; i < 4; i++)
#pragma unroll
      for (int j = 0; j < 4; j++)
        acc[i][j] = __builtin_amdgcn_mfma_f32_16x16x32_f16(af[i], bf[j], acc[i][j], 0, 0, 0);
  }
#pragma unroll
  for (int j = 0; j < 4; j++) {
    int col = col0 + 16 * j + lr;
    float bb = bias[col];
#pragma unroll
    for (int i = 0; i < 4; i++) {
#pragma unroll
      for (int r = 0; r < 4; r++) {
        int row = row0 + 16 * i + 4 * lg + r;
        float v = acc[i][j][r] + bb;
        if (act) v = 0.5f * v * (1.0f + erff(v * 0.70710678118f));
        out[(size_t)row * N + col] = (_Float16)v;
      }
    }
  }
}

// ---- output projection: A = ctx (row-major), W = woP (packed) ----
__global__ __launch_bounds__(256, 2) void outproj_kernel(
    const _Float16* __restrict__ ctxh, const _Float16* __restrict__ woP,
    const float* __restrict__ bo, float* __restrict__ out) {
  int wave = threadIdx.x >> 6, lane = threadIdx.x & 63;
  int lr = lane & 15, lg = lane >> 4;
  int row0 = blockIdx.x * 128 + (wave >> 1) * 64;
  int col0 = blockIdx.y * 128 + (wave & 1) * 64;
  int ct0 = col0 >> 4;
  const _Float16* Ap = ctxh + (size_t)(row0 + lr) * 1024 + 8 * lg;
  float4_t acc[4][4];
#pragma unroll
  for (int i = 0; i < 4; i++)
#pragma unroll
    for (int j = 0; j < 4; j++) acc[i][j] = (float4_t){0.f, 0.f, 0.f, 0.f};
  for (int ks = 0; ks < 32; ks++) {
    half8_t af[4], bf[4];
#pragma unroll
    for (int i = 0; i < 4; i++)
      af[i] = *(const half8_t*)(Ap + (size_t)(16 * i) * 1024 + 32 * ks);
#pragma unroll
    for (int j = 0; j < 4; j++)
      bf[j] = *(const half8_t*)(woP + (((size_t)(ct0 + j) * 32 + ks) << 9) + (lane << 3));
#pragma unroll
    for (int i = 0; i < 4; i++)
#pragma unroll
      for (int j = 0; j < 4; j++)
        acc[i][j] = __builtin_amdgcn_mfma_f32_16x16x32_f16(af[i], bf[j], acc[i][j], 0, 0, 0);
  }
#pragma unroll
  for (int j = 0; j < 4; j++) {
    int col = col0 + 16 * j + lr;
    float bb = bo[col];
#pragma unroll
    for (int i = 0; i < 4; i++) {
#pragma unroll
      for (int r = 0; r < 4; r++) {
        int row = row0 + 16 * i + 4 * lg + r;
        out[(size_t)row * 1024 + col] = acc[i][j][r] + bb;
      }
    }
  }
}

// ---- mechanism logits: Hm[4096,512] . Wm2[512] + bm2 ----
__global__ __launch_bounds__(256) void mech_logits_kernel(
    const _Float16* __restrict__ Hm, const float* __restrict__ Wm2,
    const float* __restrict__ bm2, float* __restrict__ logits) {
  int wave = threadIdx.x >> 6, lane = threadIdx.x & 63;
  int row = blockIdx.x * 4 + wave;
  half8_t hv = *(const half8_t*)(Hm + (size_t)row * 512 + lane * 8);
  float4_t w0 = *(const float4_t*)(Wm2 + lane * 8);
  float4_t w1 = *(const float4_t*)(Wm2 + lane * 8 + 4);
  float s = 0.f;
#pragma unroll
  for (int j = 0; j < 4; j++) s += (float)hv[j] * w0[j];
#pragma unroll
  for (int j = 0; j < 4; j++) s += (float)hv[4 + j] * w1[j];
#pragma unroll
  for (int m = 32; m >= 1; m >>= 1) s += __shfl_xor(s, m, 64);
  if (lane == 0) logits[row] = s + bm2[0];
}

// ---- per-batch softmax over 2048 logits ----
__global__ __launch_bounds__(256) void mech_softmax_kernel(
    const float* __restrict__ logits, float* __restrict__ mech_ws,
    float* __restrict__ mech_out) {
  int b = blockIdx.x;
  int t = threadIdx.x;
  int wave = t >> 6, lane = t & 63;
  __shared__ float redmax[4];
  __shared__ float redsum[4];
  const float4_t* L4 = (const float4_t*)(logits + (size_t)b * 2048);
  float4_t v0 = L4[2 * t], v1 = L4[2 * t + 1];
  float mx = fmaxf(fmaxf(fmaxf(v0[0], v0[1]), fmaxf(v0[2], v0[3])),
                   fmaxf(fmaxf(v1[0], v1[1]), fmaxf(v1[2], v1[3])));
#pragma unroll
  for (int m = 32; m >= 1; m >>= 1) mx = fmaxf(mx, __shfl_xor(mx, m, 64));
  if (lane == 0) redmax[wave] = mx;
  __syncthreads();
  mx = fmaxf(fmaxf(redmax[0], redmax[1]), fmaxf(redmax[2], redmax[3]));
  float e[8];
  float s = 0.f;
#pragma unroll
  for (int j = 0; j < 4; j++) { e[j] = __expf(v0[j] - mx); s += e[j]; }
#pragma unroll
  for (int j = 0; j < 4; j++) { e[4 + j] = __expf(v1[j] - mx); s += e[4 + j]; }
#pragma unroll
  for (int m = 32; m >= 1; m >>= 1) s += __shfl_xor(s, m, 64);
  if (lane == 0) redsum[wave] = s;
  __syncthreads();
  s = redsum[0] + redsum[1] + redsum[2] + redsum[3];
  float inv = 1.0f / s;
  size_t base = (size_t)b * 2048 + (size_t)t * 8;
#pragma unroll
  for (int j = 0; j < 8; j++) {
    float val = e[j] * inv;
    mech_ws[base + j] = val;
    mech_out[base + j] = val;
  }
}

// ---- K fragment pack: Kh[4096,1024] -> KP[bh][kt][c][lane][8] ----
__global__ __launch_bounds__(256) void kpack_kernel(const _Float16* __restrict__ Kh,
                                                    _Float16* __restrict__ KP) {
  int c = blockIdx.x * 256 + threadIdx.x;     // 524288 chunks
  int lane = c & 63;
  int c2 = (c >> 6) & 1;
  int kt = (c >> 7) & 127;
  int bh = c >> 14;
  int b = bh >> 4, h = bh & 15;
  int lr = lane & 15, lg = lane >> 4;
  const _Float16* sp = Kh + (size_t)(b * 2048 + 16 * kt + lr) * 1024 + h * 64 + 32 * c2 + 8 * lg;
  *(half8_t*)(KP + (size_t)c * 8) = *(const half8_t*)sp;
}

// ---- V fragment pack: Vh[4096,1024] -> VP[bh][kt][dd][lane][4] ----
// vf[dd][t]: lane(lr,lg) needs V[k=16kt+4lg..+3][d=16dd+lr] per (b,h).
// LDS-tiled: stage 64k x 64d tile, emit 1024 packed half4 chunks (4 reps).
__global__ __launch_bounds__(256) void vpack_kernel(const _Float16* __restrict__ Vh,
                                                    _Float16* __restrict__ VP) {
  int bh = blockIdx.y;
  int b = bh >> 4, h = bh & 15;
  int k0 = blockIdx.x * 64;
  __shared__ _Float16 tile[64][68];   // [d][k], pad 68 keeps half4 8B-aligned
  int t = threadIdx.x;
#pragma unroll
  for (int rep = 0; rep < 16; rep++) {
    int idx = rep * 256 + t;
    int k = idx >> 6, d = idx & 63;
    tile[d][k] = Vh[(size_t)(b * 2048 + k0 + k) * 1024 + h * 64 + d];
  }
  __syncthreads();
  _Float16* outb = VP + (((size_t)bh * 128 + (k0 >> 4)) << 10);  // 4kt*4dd*64lane*4
#pragma unroll
  for (int rep = 0; rep < 4; rep++) {   // 1024 chunks total (BUGFIX: was 16)
    int o4 = rep * 256 + t;             // [kt'][dd][lane], kt' in [0,4)
    int lane = o4 & 63;
    int dd = (o4 >> 6) & 3;
    int ktp = o4 >> 8;
    int d = 16 * dd + (lane & 15);
    int k = 16 * ktp + 4 * (lane >> 4);
    half4_t v = *(const half4_t*)&tile[d][k];
    *(half4_t*)(outb + (size_t)o4 * 4) = v;
  }
}

// ---- flash attention with mechanism bias (packed K/V) ----
// swapped QK^T: s = mfma(K-frag, Q-frag) -> lane holds P[q=lr][k=4*lg+r] per
// group; that IS the A-fragment of mfma_f32_16x16x16f16 for the PV step.
// All K/V fragment loads are lane-contiguous (1KB / 512B per wave).
__global__ __launch_bounds__(256, 2) void attn_kernel(
    const _Float16* __restrict__ Qh, const _Float16* __restrict__ KP,
    const _Float16* __restrict__ VP, const float* __restrict__ mech,
    const int* __restrict__ mask, _Float16* __restrict__ ctxh) {
  __shared__ float bias_s[2048];
  int bh = blockIdx.y;
  int b = bh >> 4, h = bh & 15;
  for (int i = threadIdx.x; i < 2048; i += 256)
    bias_s[i] = 2.0f * mech[(size_t)b * 2048 + i] +
                (mask[(size_t)b * 2048 + i] != 0 ? 0.0f : -1e30f);
  __syncthreads();
  int wave = threadIdx.x >> 6, lane = threadIdx.x & 63;
  int lr = lane & 15, lg = lane >> 4;
  int q0 = blockIdx.x * 128 + wave * 32;   // 32 q-rows per wave

  const _Float16* Qbase = Qh + (size_t)(b * 2048 + q0 + lr) * 1024 + h * 64 + 8 * lg;
  half8_t qf[2][2];
  qf[0][0] = *(const half8_t*)(Qbase);
  qf[0][1] = *(const half8_t*)(Qbase + 32);
  qf[1][0] = *(const half8_t*)(Qbase + (size_t)16 * 1024);
  qf[1][1] = *(const half8_t*)(Qbase + (size_t)16 * 1024 + 32);
  const _Float16* KPbh = KP + ((size_t)bh << 17);   // 128kt*2c*64*8
  const _Float16* VPbh = VP + ((size_t)bh << 17);   // 128kt*4dd*64*4

  float m0 = -1e30f, m1 = -1e30f;
  float l0 = 0.0f, l1 = 0.0f;
  float4_t cacc[2][4];
#pragma unroll
  for (int g = 0; g < 2; g++)
#pragma unroll
    for (int dd = 0; dd < 4; dd++) cacc[g][dd] = (float4_t){0.f, 0.f, 0.f, 0.f};

  for (int k0 = 0; k0 < 2048; k0 += 64) {
    int kt0 = k0 >> 4;
    // ---- batched lane-contiguous loads ----
    half8_t kf[4][2];
#pragma unroll
    for (int t = 0; t < 4; t++) {
      kf[t][0] = *(const half8_t*)(KPbh + (((size_t)(kt0 + t) * 2 + 0) << 9) + (lane << 3));
      kf[t][1] = *(const half8_t*)(KPbh + (((size_t)(kt0 + t) * 2 + 1) << 9) + (lane << 3));
    }
    half4_t vf[4][4];   // [dd][t]
#pragma unroll
    for (int dd = 0; dd < 4; dd++)
#pragma unroll
      for (int t = 0; t < 4; t++)
        vf[dd][t] = *(const half4_t*)(VPbh + (((size_t)(kt0 + t) * 4 + dd) << 8) + (lane << 2));
    float4_t bias4[4];
#pragma unroll
    for (int t = 0; t < 4; t++)
      bias4[t] = *(const float4_t*)&bias_s[k0 + 16 * t + 4 * lg];
    // ---- QK^T for both q-groups (K frags reused) ----
    float4_t s0[4], s1[4];
#pragma unroll
    for (int t = 0; t < 4; t++) {
      float4_t z = (float4_t){0.f, 0.f, 0.f, 0.f};
      z = __builtin_amdgcn_mfma_f32_16x16x32_f16(kf[t][0], qf[0][0], z, 0, 0, 0);
      z = __builtin_amdgcn_mfma_f32_16x16x32_f16(kf[t][1], qf[0][1], z, 0, 0, 0);
      s0[t] = z;
      float4_t w = (float4_t){0.f, 0.f, 0.f, 0.f};
      w = __builtin_amdgcn_mfma_f32_16x16x32_f16(kf[t][0], qf[1][0], w, 0, 0, 0);
      w = __builtin_amdgcn_mfma_f32_16x16x32_f16(kf[t][1], qf[1][1], w, 0, 0, 0);
      s1[t] = w;
    }
#pragma unroll
    for (int t = 0; t < 4; t++)
#pragma unroll
      for (int r = 0; r < 4; r++) {
        s0[t][r] = s0[t][r] * 0.125f + bias4[t][r];
        s1[t][r] = s1[t][r] * 0.125f + bias4[t][r];
      }
    // ---- per-group tile max ----
    float tm0 = s0[0][0], tm1 = s1[0][0];
#pragma unroll
    for (int t = 0; t < 4; t++)
#pragma unroll
      for (int r = 0; r < 4; r++) {
        tm0 = fmaxf(tm0, s0[t][r]);
        tm1 = fmaxf(tm1, s1[t][r]);
      }
    tm0 = fmaxf(tm0, __shfl_xor(tm0, 16, 64));
    tm0 = fmaxf(tm0, __shfl_xor(tm0, 32, 64));
    tm1 = fmaxf(tm1, __shfl_xor(tm1, 16, 64));
    tm1 = fmaxf(tm1, __shfl_xor(tm1, 32, 64));
    // ---- defer-max: rare rescale ----
    if (__any((tm0 > m0 + 8.0f) || (tm1 > m1 + 8.0f))) {
      float mn0 = fmaxf(m0, tm0), mn1 = fmaxf(m1, tm1);
      float a0 = __expf(m0 - mn0), a1 = __expf(m1 - mn1);
      l0 *= a0; l1 *= a1;
      m0 = mn0; m1 = mn1;
      int rbase = 4 * lg;
#pragma unroll
      for (int r = 0; r < 4; r++) {
        float b0 = __shfl(a0, rbase + r, 64);
        float b1 = __shfl(a1, rbase + r, 64);
#pragma unroll
        for (int dd = 0; dd < 4; dd++) {
          cacc[0][dd][r] *= b0;
          cacc[1][dd][r] *= b1;
        }
      }
    }
    // ---- P = exp(sc - m), per-lane partial l, f16 pack ----
    half4_t pa0[4], pa1[4];
#pragma unroll
    for (int t = 0; t < 4; t++) {
#pragma unroll
      for (int r = 0; r < 4; r++) {
        float p0 = __expf(s0[t][r] - m0);
        float p1 = __expf(s1[t][r] - m1);
        l0 += p0; l1 += p1;
        pa0[t][r] = (_Float16)p0;
        pa1[t][r] = (_Float16)p1;
      }
    }
    // ---- PV for both groups (V frags reused) ----
#pragma unroll
    for (int dd = 0; dd < 4; dd++)
#pragma unroll
      for (int t = 0; t < 4; t++) {
        cacc[0][dd] = __builtin_amdgcn_mfma_f32_16x16x16f16(pa0[t], vf[dd][t], cacc[0][dd], 0, 0, 0);
        cacc[1][dd] = __builtin_amdgcn_mfma_f32_16x16x16f16(pa1[t], vf[dd][t], cacc[1][dd], 0, 0, 0);
      }
  }
  // ---- finalize both groups ----
  l0 += __shfl_xor(l0, 16, 64);
  l0 += __shfl_xor(l0, 32, 64);
  l1 += __shfl_xor(l1, 16, 64);
  l1 += __shfl_xor(l1, 32, 64);
  float li0 = 1.0f / l0, li1 = 1.0f / l1;
  int rbase = 4 * lg;
#pragma unroll
  for (int r = 0; r < 4; r++) {
    float i0 = __shfl(li0, rbase + r, 64);
    float i1 = __shfl(li1, rbase + r, 64);
#pragma unroll
    for (int dd = 0; dd < 4; dd++) {
      size_t idx0 = (size_t)(b * 2048 + q0 + rbase + r) * 1024 + h * 64 + 16 * dd + lr;
      size_t idx1 = (size_t)(b * 2048 + q0 + 16 + rbase + r) * 1024 + h * 64 + 16 * dd + lr;
      ctxh[idx0] = (_Float16)(cacc[0][dd][r] * i0);
      ctxh[idx1] = (_Float16)(cacc[1][dd][r] * i1);
    }
  }
}

extern "C" void kernel_launch(void* const* d_in, const int* in_sizes, int n_in,
                              void* d_out, int out_size, void* d_ws, size_t ws_size,
                              hipStream_t stream) {
  const float* x    = (const float*)d_in[0];
  const int*   mask = (const int*)d_in[1];
  const float* Wq   = (const float*)d_in[2];
  const float* bq   = (const float*)d_in[3];
  const float* Wk   = (const float*)d_in[4];
  const float* bk   = (const float*)d_in[5];
  const float* Wv   = (const float*)d_in[6];
  const float* bv   = (const float*)d_in[7];
  const float* Wo   = (const float*)d_in[8];
  const float* bo   = (const float*)d_in[9];
  const float* Wm1  = (const float*)d_in[10];
  const float* bm1  = (const float*)d_in[11];
  const float* Wm2  = (const float*)d_in[12];
  const float* bm2  = (const float*)d_in[13];
  float* outp = (float*)d_out;
  float* mech_out = outp + (size_t)MTOT * DMODEL;

  char* ws = (char*)d_ws;
  _Float16* xP   = (_Float16*)(ws + 0);          // 8.4MB; reused as KP after proj
  _Float16* wqP  = (_Float16*)(ws + 8388608);
  _Float16* wkP  = (_Float16*)(ws + 10485760);
  _Float16* wvP  = (_Float16*)(ws + 12582912);
  _Float16* woP  = (_Float16*)(ws + 14680064);
  _Float16* wm1P = (_Float16*)(ws + 16777216);
  _Float16* Qh   = (_Float16*)(ws + 17825792);
  _Float16* Kh   = (_Float16*)(ws + 26214400);
  _Float16* Vh   = (_Float16*)(ws + 34603008);
  _Float16* VP   = (_Float16*)(ws + 42991616);
  _Float16* ctxh = (_Float16*)(ws + 51380224);
  _Float16* Hm   = (_Float16*)(ws + 59768832);
  float* logits  = (float*)(ws + 63963136);
  float* mech_ws = (float*)(ws + 63979520);
  _Float16* KPp  = xP;   // alias: x packed is dead once proj completes

  hipLaunchKernelGGL(pack_all_kernel, dim3(2304, 2), dim3(256), 0, stream,
                     x, Wq, Wk, Wv, Wo, Wm1, xP, wqP, wkP, wvP, woP, wm1P);

  hipLaunchKernelGGL(proj_kernel, dim3(32, 8, 4), dim3(256), 0, stream,
                     xP, wqP, wkP, wvP, wm1P, bq, bk, bv, bm1, Qh, Kh, Vh, Hm);

  hipLaunchKernelGGL(mech_logits_kernel, dim3(1024), dim3(256), 0, stream,
                     Hm, Wm2, bm2, logits);
  hipLaunchKernelGGL(mech_softmax_kernel, dim3(2), dim3(256), 0, stream,
                     logits, mech_ws, mech_out);

  hipLaunchKernelGGL(kpack_kernel, dim3(2048), dim3(256), 0, stream, Kh, KPp);
  hipLaunchKernelGGL(vpack_kernel, dim3(32, 32), dim3(256), 0, stream, Vh, VP);

  hipLaunchKernelGGL(attn_kernel, dim3(16, 32), dim3(256), 0, stream,
                     Qh, KPp, VP, mech_ws, mask, ctxh);

  hipLaunchKernelGGL(outproj_kernel, dim3(32, 8), dim3(256), 0, stream,
                     ctxh, woP, bo, outp);
}

// Round 9
// 263.428 us; speedup vs baseline: 2.4063x; 1.0432x over previous
//
#include <hip/hip_runtime.h>
#include <hip/hip_fp16.h>
#include <math.h>

typedef _Float16 half4_t __attribute__((ext_vector_type(4)));
typedef _Float16 half8_t __attribute__((ext_vector_type(8)));
typedef float float4_t __attribute__((ext_vector_type(4)));

static constexpr int DMODEL = 1024;
static constexpr int SLEN   = 2048;
static constexpr int NHEADS = 16;
static constexpr int MTOT   = 4096;   // B * S

// ============================================================================
// Fragment-packed operand layout (transaction minimization):
//   P[rt][ks][lane][8] for a row-major [R][K] NT-GEMM operand:
//     element (row, col): rt=row/16, ks=col/32, lane=((col%32)/8)*16 + row%16,
//     j=col%8.  One wave fragment load = lane*16B contiguous (1KB, 8 lines).
// ============================================================================

// ---- f32 -> f16 convert + fragment-pack (x + all 5 weights) ----
__global__ __launch_bounds__(256) void pack_all_kernel(
    const float* __restrict__ x,
    const float* __restrict__ Wq, const float* __restrict__ Wk,
    const float* __restrict__ Wv, const float* __restrict__ Wo,
    const float* __restrict__ Wm1,
    _Float16* __restrict__ xP, _Float16* __restrict__ wqP,
    _Float16* __restrict__ wkP, _Float16* __restrict__ wvP,
    _Float16* __restrict__ woP, _Float16* __restrict__ wm1P) {
  int bx = blockIdx.x;
  const float* src; _Float16* dst; int lb;
  if (blockIdx.y == 0) {
    if (bx >= 2048) return;
    src = x; dst = xP; lb = bx;
  } else {
    if (bx < 512)       { src = Wq;  dst = wqP;  lb = bx; }
    else if (bx < 1024) { src = Wk;  dst = wkP;  lb = bx - 512; }
    else if (bx < 1536) { src = Wv;  dst = wvP;  lb = bx - 1024; }
    else if (bx < 2048) { src = Wo;  dst = woP;  lb = bx - 1536; }
    else                { src = Wm1; dst = wm1P; lb = bx - 2048; }
  }
  int c = lb * 256 + threadIdx.x;     // chunk id
  int lane = c & 63;
  int ks = (c >> 6) & 31;             // K = 1024 -> 32 k-steps
  int rt = c >> 11;
  int row = 16 * rt + (lane & 15);
  int col = 32 * ks + 8 * (lane >> 4);
  const float* sp = src + (size_t)row * 1024 + col;
  float4_t v0 = *(const float4_t*)sp;
  float4_t v1 = *(const float4_t*)(sp + 4);
  half8_t h;
  h[0] = (_Float16)v0[0]; h[1] = (_Float16)v0[1];
  h[2] = (_Float16)v0[2]; h[3] = (_Float16)v0[3];
  h[4] = (_Float16)v1[0]; h[5] = (_Float16)v1[1];
  h[6] = (_Float16)v1[2]; h[7] = (_Float16)v1[3];
  *(half8_t*)(dst + (size_t)c * 8) = h;
}

// ---- fused QKV + MLP1 projections (packed A, packed W, reg-dbuf pipeline) --
__global__ __launch_bounds__(256, 2) void proj_kernel(
    const _Float16* __restrict__ xP,
    const _Float16* __restrict__ wqP, const _Float16* __restrict__ wkP,
    const _Float16* __restrict__ wvP, const _Float16* __restrict__ wm1P,
    const float* __restrict__ bq, const float* __restrict__ bk,
    const float* __restrict__ bv, const float* __restrict__ bm1,
    _Float16* __restrict__ Qh, _Float16* __restrict__ Kh,
    _Float16* __restrict__ Vh, _Float16* __restrict__ Hm) {
  int z = blockIdx.z;
  const _Float16* W; const float* bias; _Float16* out; int N; bool act = false;
  if (z == 0)      { W = wqP;  bias = bq;  out = Qh; N = 1024; }
  else if (z == 1) { W = wkP;  bias = bk;  out = Kh; N = 1024; }
  else if (z == 2) { W = wvP;  bias = bv;  out = Vh; N = 1024; }
  else             { W = wm1P; bias = bm1; out = Hm; N = 512; act = true; }
  int colB = blockIdx.y * 128;
  if (colB >= N) return;
  int wave = threadIdx.x >> 6, lane = threadIdx.x & 63;
  int lr = lane & 15, lg = lane >> 4;
  int row0 = blockIdx.x * 128 + (wave >> 1) * 64;
  int col0 = colB + (wave & 1) * 64;
  int rt0 = row0 >> 4, ct0 = col0 >> 4;
  const _Float16* Ab = xP + (((size_t)rt0 * 32) << 9) + (lane << 3);
  const _Float16* Bb = W  + (((size_t)ct0 * 32) << 9) + (lane << 3);
  float4_t acc[4][4];
#pragma unroll
  for (int i = 0; i < 4; i++)
#pragma unroll
    for (int j = 0; j < 4; j++) acc[i][j] = (float4_t){0.f, 0.f, 0.f, 0.f};
  half8_t aP[4], bP[4], aN[4], bN[4];
#pragma unroll
  for (int i = 0; i < 4; i++) {
    aP[i] = *(const half8_t*)(Ab + ((size_t)(i * 32) << 9));
    bP[i] = *(const half8_t*)(Bb + ((size_t)(i * 32) << 9));
  }
  for (int ks = 0; ks < 30; ks += 2) {
#pragma unroll
    for (int i = 0; i < 4; i++) {
      aN[i] = *(const half8_t*)(Ab + ((size_t)(i * 32 + ks + 1) << 9));
      bN[i] = *(const half8_t*)(Bb + ((size_t)(i * 32 + ks + 1) << 9));
    }
#pragma unroll
    for (int i = 0; i < 4; i++)
#pragma unroll
      for (int j = 0; j < 4; j++)
        acc[i][j] = __builtin_amdgcn_mfma_f32_16x16x32_f16(aP[i], bP[j], acc[i][j], 0, 0, 0);
#pragma unroll
    for (int i = 0; i < 4; i++) {
      aP[i] = *(const half8_t*)(Ab + ((size_t)(i * 32 + ks + 2) << 9));
      bP[i] = *(const half8_t*)(Bb + ((size_t)(i * 32 + ks + 2) << 9));
    }
#pragma unroll
    for (int i = 0; i < 4; i++)
#pragma unroll
      for (int j = 0; j < 4; j++)
        acc[i][j] = __builtin_amdgcn_mfma_f32_16x16x32_f16(aN[i], bN[j], acc[i][j], 0, 0, 0);
  }
  // tail: ks = 30 (in aP), 31
#pragma unroll
  for (int i = 0; i < 4; i++) {
    aN[i] = *(const half8_t*)(Ab + ((size_t)(i * 32 + 31) << 9));
    bN[i] = *(const half8_t*)(Bb + ((size_t)(i * 32 + 31) << 9));
  }
#pragma unroll
  for (int i = 0; i < 4; i++)
#pragma unroll
    for (int j = 0; j < 4; j++)
      acc[i][j] = __builtin_amdgcn_mfma_f32_16x16x32_f16(aP[i], bP[j], acc[i][j], 0, 0, 0);
#pragma unroll
  for (int i = 0; i < 4; i++)
#pragma unroll
    for (int j = 0; j < 4; j++)
      acc[i][j] = __builtin_amdgcn_mfma_f32_16x16x32_f16(aN[i], bN[j], acc[i][j], 0, 0, 0);
#pragma unroll
  for (int j = 0; j < 4; j++) {
    int col = col0 + 16 * j + lr;
    float bb = bias[col];
#pragma unroll
    for (int i = 0; i < 4; i++) {
#pragma unroll
      for (int r = 0; r < 4; r++) {
        int row = row0 + 16 * i + 4 * lg + r;
        float v = acc[i][j][r] + bb;
        if (act) v = 0.5f * v * (1.0f + erff(v * 0.70710678118f));
        out[(size_t)row * N + col] = (_Float16)v;
      }
    }
  }
}

// ---- output projection: A = ctxP (packed), W = woP (packed), pipelined ----
__global__ __launch_bounds__(256, 2) void outproj_kernel(
    const _Float16* __restrict__ ctxP, const _Float16* __restrict__ woP,
    const float* __restrict__ bo, float* __restrict__ out) {
  int wave = threadIdx.x >> 6, lane = threadIdx.x & 63;
  int lr = lane & 15, lg = lane >> 4;
  int row0 = blockIdx.x * 128 + (wave >> 1) * 64;
  int col0 = blockIdx.y * 128 + (wave & 1) * 64;
  int rt0 = row0 >> 4, ct0 = col0 >> 4;
  const _Float16* Ab = ctxP + (((size_t)rt0 * 32) << 9) + (lane << 3);
  const _Float16* Bb = woP  + (((size_t)ct0 * 32) << 9) + (lane << 3);
  float4_t acc[4][4];
#pragma unroll
  for (int i = 0; i < 4; i++)
#pragma unroll
    for (int j = 0; j < 4; j++) acc[i][j] = (float4_t){0.f, 0.f, 0.f, 0.f};
  half8_t aP[4], bP[4], aN[4], bN[4];
#pragma unroll
  for (int i = 0; i < 4; i++) {
    aP[i] = *(const half8_t*)(Ab + ((size_t)(i * 32) << 9));
    bP[i] = *(const half8_t*)(Bb + ((size_t)(i * 32) << 9));
  }
  for (int ks = 0; ks < 30; ks += 2) {
#pragma unroll
    for (int i = 0; i < 4; i++) {
      aN[i] = *(const half8_t*)(Ab + ((size_t)(i * 32 + ks + 1) << 9));
      bN[i] = *(const half8_t*)(Bb + ((size_t)(i * 32 + ks + 1) << 9));
    }
#pragma unroll
    for (int i = 0; i < 4; i++)
#pragma unroll
      for (int j = 0; j < 4; j++)
        acc[i][j] = __builtin_amdgcn_mfma_f32_16x16x32_f16(aP[i], bP[j], acc[i][j], 0, 0, 0);
#pragma unroll
    for (int i = 0; i < 4; i++) {
      aP[i] = *(const half8_t*)(Ab + ((size_t)(i * 32 + ks + 2) << 9));
      bP[i] = *(const half8_t*)(Bb + ((size_t)(i * 32 + ks + 2) << 9));
    }
#pragma unroll
    for (int i = 0; i < 4; i++)
#pragma unroll
      for (int j = 0; j < 4; j++)
        acc[i][j] = __builtin_amdgcn_mfma_f32_16x16x32_f16(aN[i], bN[j], acc[i][j], 0, 0, 0);
  }
#pragma unroll
  for (int i = 0; i < 4; i++) {
    aN[i] = *(const half8_t*)(Ab + ((size_t)(i * 32 + 31) << 9));
    bN[i] = *(const half8_t*)(Bb + ((size_t)(i * 32 + 31) << 9));
  }
#pragma unroll
  for (int i = 0; i < 4; i++)
#pragma unroll
    for (int j = 0; j < 4; j++)
      acc[i][j] = __builtin_amdgcn_mfma_f32_16x16x32_f16(aP[i], bP[j], acc[i][j], 0, 0, 0);
#pragma unroll
  for (int i = 0; i < 4; i++)
#pragma unroll
    for (int j = 0; j < 4; j++)
      acc[i][j] = __builtin_amdgcn_mfma_f32_16x16x32_f16(aN[i], bN[j], acc[i][j], 0, 0, 0);
#pragma unroll
  for (int j = 0; j < 4; j++) {
    int col = col0 + 16 * j + lr;
    float bb = bo[col];
#pragma unroll
    for (int i = 0; i < 4; i++) {
#pragma unroll
      for (int r = 0; r < 4; r++) {
        int row = row0 + 16 * i + 4 * lg + r;
        out[(size_t)row * 1024 + col] = acc[i][j][r] + bb;
      }
    }
  }
}

// ---- mechanism logits: Hm[4096,512] . Wm2[512] + bm2 ----
__global__ __launch_bounds__(256) void mech_logits_kernel(
    const _Float16* __restrict__ Hm, const float* __restrict__ Wm2,
    const float* __restrict__ bm2, float* __restrict__ logits) {
  int wave = threadIdx.x >> 6, lane = threadIdx.x & 63;
  int row = blockIdx.x * 4 + wave;
  half8_t hv = *(const half8_t*)(Hm + (size_t)row * 512 + lane * 8);
  float4_t w0 = *(const float4_t*)(Wm2 + lane * 8);
  float4_t w1 = *(const float4_t*)(Wm2 + lane * 8 + 4);
  float s = 0.f;
#pragma unroll
  for (int j = 0; j < 4; j++) s += (float)hv[j] * w0[j];
#pragma unroll
  for (int j = 0; j < 4; j++) s += (float)hv[4 + j] * w1[j];
#pragma unroll
  for (int m = 32; m >= 1; m >>= 1) s += __shfl_xor(s, m, 64);
  if (lane == 0) logits[row] = s + bm2[0];
}

// ---- per-batch softmax over 2048 logits ----
__global__ __launch_bounds__(256) void mech_softmax_kernel(
    const float* __restrict__ logits, float* __restrict__ mech_ws,
    float* __restrict__ mech_out) {
  int b = blockIdx.x;
  int t = threadIdx.x;
  int wave = t >> 6, lane = t & 63;
  __shared__ float redmax[4];
  __shared__ float redsum[4];
  const float4_t* L4 = (const float4_t*)(logits + (size_t)b * 2048);
  float4_t v0 = L4[2 * t], v1 = L4[2 * t + 1];
  float mx = fmaxf(fmaxf(fmaxf(v0[0], v0[1]), fmaxf(v0[2], v0[3])),
                   fmaxf(fmaxf(v1[0], v1[1]), fmaxf(v1[2], v1[3])));
#pragma unroll
  for (int m = 32; m >= 1; m >>= 1) mx = fmaxf(mx, __shfl_xor(mx, m, 64));
  if (lane == 0) redmax[wave] = mx;
  __syncthreads();
  mx = fmaxf(fmaxf(redmax[0], redmax[1]), fmaxf(redmax[2], redmax[3]));
  float e[8];
  float s = 0.f;
#pragma unroll
  for (int j = 0; j < 4; j++) { e[j] = __expf(v0[j] - mx); s += e[j]; }
#pragma unroll
  for (int j = 0; j < 4; j++) { e[4 + j] = __expf(v1[j] - mx); s += e[4 + j]; }
#pragma unroll
  for (int m = 32; m >= 1; m >>= 1) s += __shfl_xor(s, m, 64);
  if (lane == 0) redsum[wave] = s;
  __syncthreads();
  s = redsum[0] + redsum[1] + redsum[2] + redsum[3];
  float inv = 1.0f / s;
  size_t base = (size_t)b * 2048 + (size_t)t * 8;
#pragma unroll
  for (int j = 0; j < 8; j++) {
    float val = e[j] * inv;
    mech_ws[base + j] = val;
    mech_out[base + j] = val;
  }
}

// ---- K fragment pack: Kh[4096,1024] -> KP[bh][kt][c][lane][8] ----
__global__ __launch_bounds__(256) void kpack_kernel(const _Float16* __restrict__ Kh,
                                                    _Float16* __restrict__ KP) {
  int c = blockIdx.x * 256 + threadIdx.x;     // 524288 chunks
  int lane = c & 63;
  int c2 = (c >> 6) & 1;
  int kt = (c >> 7) & 127;
  int bh = c >> 14;
  int b = bh >> 4, h = bh & 15;
  int lr = lane & 15, lg = lane >> 4;
  const _Float16* sp = Kh + (size_t)(b * 2048 + 16 * kt + lr) * 1024 + h * 64 + 32 * c2 + 8 * lg;
  *(half8_t*)(KP + (size_t)c * 8) = *(const half8_t*)sp;
}

// ---- V fragment pack: Vh[4096,1024] -> VP[bh][kt][dd][lane][4] ----
__global__ __launch_bounds__(256) void vpack_kernel(const _Float16* __restrict__ Vh,
                                                    _Float16* __restrict__ VP) {
  int bh = blockIdx.y;
  int b = bh >> 4, h = bh & 15;
  int k0 = blockIdx.x * 64;
  __shared__ _Float16 tile[64][68];   // [d][k]
  int t = threadIdx.x;
#pragma unroll
  for (int rep = 0; rep < 16; rep++) {
    int idx = rep * 256 + t;
    int k = idx >> 6, d = idx & 63;
    tile[d][k] = Vh[(size_t)(b * 2048 + k0 + k) * 1024 + h * 64 + d];
  }
  __syncthreads();
  _Float16* outb = VP + (((size_t)bh * 128 + (k0 >> 4)) << 10);
#pragma unroll
  for (int rep = 0; rep < 4; rep++) {   // 1024 chunks total
    int o4 = rep * 256 + t;             // [kt'][dd][lane]
    int lane = o4 & 63;
    int dd = (o4 >> 6) & 3;
    int ktp = o4 >> 8;
    int d = 16 * dd + (lane & 15);
    int k = 16 * ktp + 4 * (lane >> 4);
    half4_t v = *(const half4_t*)&tile[d][k];
    *(half4_t*)(outb + (size_t)o4 * 4) = v;
  }
}

// ---- flash attention with mechanism bias (packed K/V, packed ctx out) ----
// swapped QK^T: s = mfma(K-frag, Q-frag) -> lane holds P[q=lr][k=4*lg+r] per
// group; that IS the A-fragment of mfma_f32_16x16x16f16 for the PV step.
// Epilogue: per-wave LDS repack -> ctx written fragment-packed (4x dwordx4
// stores/wave instead of 32 scalar) for outproj's lane-contiguous A loads.
__global__ __launch_bounds__(256, 2) void attn_kernel(
    const _Float16* __restrict__ Qh, const _Float16* __restrict__ KP,
    const _Float16* __restrict__ VP, const float* __restrict__ mech,
    const int* __restrict__ mask, _Float16* __restrict__ ctxP) {
  __shared__ float bias_s[2048];
  __shared__ _Float16 ep[4][4][512];   // [wave][chunk][lane*8+j]
  int bh = blockIdx.y;
  int b = bh >> 4, h = bh & 15;
  for (int i = threadIdx.x; i < 2048; i += 256)
    bias_s[i] = 2.0f * mech[(size_t)b * 2048 + i] +
                (mask[(size_t)b * 2048 + i] != 0 ? 0.0f : -1e30f);
  __syncthreads();
  int wave = threadIdx.x >> 6, lane = threadIdx.x & 63;
  int lr = lane & 15, lg = lane >> 4;
  int q0 = blockIdx.x * 128 + wave * 32;   // 32 q-rows per wave

  const _Float16* Qbase = Qh + (size_t)(b * 2048 + q0 + lr) * 1024 + h * 64 + 8 * lg;
  half8_t qf[2][2];
  qf[0][0] = *(const half8_t*)(Qbase);
  qf[0][1] = *(const half8_t*)(Qbase + 32);
  qf[1][0] = *(const half8_t*)(Qbase + (size_t)16 * 1024);
  qf[1][1] = *(const half8_t*)(Qbase + (size_t)16 * 1024 + 32);
  const _Float16* KPbh = KP + ((size_t)bh << 17);
  const _Float16* VPbh = VP + ((size_t)bh << 17);

  float m0 = -1e30f, m1 = -1e30f;
  float l0 = 0.0f, l1 = 0.0f;
  float4_t cacc[2][4];
#pragma unroll
  for (int g = 0; g < 2; g++)
#pragma unroll
    for (int dd = 0; dd < 4; dd++) cacc[g][dd] = (float4_t){0.f, 0.f, 0.f, 0.f};

  for (int k0 = 0; k0 < 2048; k0 += 64) {
    int kt0 = k0 >> 4;
    half8_t kf[4][2];
#pragma unroll
    for (int t = 0; t < 4; t++) {
      kf[t][0] = *(const half8_t*)(KPbh + (((size_t)(kt0 + t) * 2 + 0) << 9) + (lane << 3));
      kf[t][1] = *(const half8_t*)(KPbh + (((size_t)(kt0 + t) * 2 + 1) << 9) + (lane << 3));
    }
    half4_t vf[4][4];   // [dd][t]
#pragma unroll
    for (int dd = 0; dd < 4; dd++)
#pragma unroll
      for (int t = 0; t < 4; t++)
        vf[dd][t] = *(const half4_t*)(VPbh + (((size_t)(kt0 + t) * 4 + dd) << 8) + (lane << 2));
    float4_t bias4[4];
#pragma unroll
    for (int t = 0; t < 4; t++)
      bias4[t] = *(const float4_t*)&bias_s[k0 + 16 * t + 4 * lg];
    float4_t s0[4], s1[4];
#pragma unroll
    for (int t = 0; t < 4; t++) {
      float4_t z = (float4_t){0.f, 0.f, 0.f, 0.f};
      z = __builtin_amdgcn_mfma_f32_16x16x32_f16(kf[t][0], qf[0][0], z, 0, 0, 0);
      z = __builtin_amdgcn_mfma_f32_16x16x32_f16(kf[t][1], qf[0][1], z, 0, 0, 0);
      s0[t] = z;
      float4_t w = (float4_t){0.f, 0.f, 0.f, 0.f};
      w = __builtin_amdgcn_mfma_f32_16x16x32_f16(kf[t][0], qf[1][0], w, 0, 0, 0);
      w = __builtin_amdgcn_mfma_f32_16x16x32_f16(kf[t][1], qf[1][1], w, 0, 0, 0);
      s1[t] = w;
    }
#pragma unroll
    for (int t = 0; t < 4; t++)
#pragma unroll
      for (int r = 0; r < 4; r++) {
        s0[t][r] = s0[t][r] * 0.125f + bias4[t][r];
        s1[t][r] = s1[t][r] * 0.125f + bias4[t][r];
      }
    float tm0 = s0[0][0], tm1 = s1[0][0];
#pragma unroll
    for (int t = 0; t < 4; t++)
#pragma unroll
      for (int r = 0; r < 4; r++) {
        tm0 = fmaxf(tm0, s0[t][r]);
        tm1 = fmaxf(tm1, s1[t][r]);
      }
    tm0 = fmaxf(tm0, __shfl_xor(tm0, 16, 64));
    tm0 = fmaxf(tm0, __shfl_xor(tm0, 32, 64));
    tm1 = fmaxf(tm1, __shfl_xor(tm1, 16, 64));
    tm1 = fmaxf(tm1, __shfl_xor(tm1, 32, 64));
    if (__any((tm0 > m0 + 8.0f) || (tm1 > m1 + 8.0f))) {
      float mn0 = fmaxf(m0, tm0), mn1 = fmaxf(m1, tm1);
      float a0 = __expf(m0 - mn0), a1 = __expf(m1 - mn1);
      l0 *= a0; l1 *= a1;
      m0 = mn0; m1 = mn1;
      int rbase = 4 * lg;
#pragma unroll
      for (int r = 0; r < 4; r++) {
        float b0 = __shfl(a0, rbase + r, 64);
        float b1 = __shfl(a1, rbase + r, 64);
#pragma unroll
        for (int dd = 0; dd < 4; dd++) {
          cacc[0][dd][r] *= b0;
          cacc[1][dd][r] *= b1;
        }
      }
    }
    half4_t pa0[4], pa1[4];
#pragma unroll
    for (int t = 0; t < 4; t++) {
#pragma unroll
      for (int r = 0; r < 4; r++) {
        float p0 = __expf(s0[t][r] - m0);
        float p1 = __expf(s1[t][r] - m1);
        l0 += p0; l1 += p1;
        pa0[t][r] = (_Float16)p0;
        pa1[t][r] = (_Float16)p1;
      }
    }
#pragma unroll
    for (int dd = 0; dd < 4; dd++)
#pragma unroll
      for (int t = 0; t < 4; t++) {
        cacc[0][dd] = __builtin_amdgcn_mfma_f32_16x16x16f16(pa0[t], vf[dd][t], cacc[0][dd], 0, 0, 0);
        cacc[1][dd] = __builtin_amdgcn_mfma_f32_16x16x16f16(pa1[t], vf[dd][t], cacc[1][dd], 0, 0, 0);
      }
  }
  // ---- finalize: normalize, pack to LDS, 4 wide stores ----
  l0 += __shfl_xor(l0, 16, 64);
  l0 += __shfl_xor(l0, 32, 64);
  l1 += __shfl_xor(l1, 16, 64);
  l1 += __shfl_xor(l1, 32, 64);
  float li0 = 1.0f / l0, li1 = 1.0f / l1;
  int rbase = 4 * lg;
  float inv0[4], inv1[4];
#pragma unroll
  for (int r = 0; r < 4; r++) {
    inv0[r] = __shfl(li0, rbase + r, 64);
    inv1[r] = __shfl(li1, rbase + r, 64);
  }
  // packed position for C element (row_local = g*16 + rbase + r,
  // col = h*64 + 16*dd + lr): chunk = g*2 + (dd>>1),
  // lane' = ((dd&1)*2 + (lr>>3))*16 + rbase + r, j = lr&7.
#pragma unroll
  for (int dd = 0; dd < 4; dd++) {
    int lanep = ((dd & 1) * 2 + (lr >> 3)) * 16 + rbase;
#pragma unroll
    for (int r = 0; r < 4; r++) {
      ep[wave][0 + (dd >> 1)][(lanep + r) * 8 + (lr & 7)] = (_Float16)(cacc[0][dd][r] * inv0[r]);
      ep[wave][2 + (dd >> 1)][(lanep + r) * 8 + (lr & 7)] = (_Float16)(cacc[1][dd][r] * inv1[r]);
    }
  }
  int rtbase = (b * 2048 + q0) >> 4;
#pragma unroll
  for (int c = 0; c < 4; c++) {
    half8_t v = *(const half8_t*)&ep[wave][c][lane * 8];
    size_t chunkid = (size_t)(rtbase + (c >> 1)) * 32 + (2 * h + (c & 1));
    *(half8_t*)(ctxP + (chunkid << 9) + (lane << 3)) = v;
  }
}

extern "C" void kernel_launch(void* const* d_in, const int* in_sizes, int n_in,
                              void* d_out, int out_size, void* d_ws, size_t ws_size,
                              hipStream_t stream) {
  const float* x    = (const float*)d_in[0];
  const int*   mask = (const int*)d_in[1];
  const float* Wq   = (const float*)d_in[2];
  const float* bq   = (const float*)d_in[3];
  const float* Wk   = (const float*)d_in[4];
  const float* bk   = (const float*)d_in[5];
  const float* Wv   = (const float*)d_in[6];
  const float* bv   = (const float*)d_in[7];
  const float* Wo   = (const float*)d_in[8];
  const float* bo   = (const float*)d_in[9];
  const float* Wm1  = (const float*)d_in[10];
  const float* bm1  = (const float*)d_in[11];
  const float* Wm2  = (const float*)d_in[12];
  const float* bm2  = (const float*)d_in[13];
  float* outp = (float*)d_out;
  float* mech_out = outp + (size_t)MTOT * DMODEL;

  char* ws = (char*)d_ws;
  _Float16* xP   = (_Float16*)(ws + 0);          // 8.4MB; reused as KP after proj
  _Float16* wqP  = (_Float16*)(ws + 8388608);
  _Float16* wkP  = (_Float16*)(ws + 10485760);
  _Float16* wvP  = (_Float16*)(ws + 12582912);
  _Float16* woP  = (_Float16*)(ws + 14680064);
  _Float16* wm1P = (_Float16*)(ws + 16777216);
  _Float16* Qh   = (_Float16*)(ws + 17825792);
  _Float16* Kh   = (_Float16*)(ws + 26214400);
  _Float16* Vh   = (_Float16*)(ws + 34603008);
  _Float16* VP   = (_Float16*)(ws + 42991616);
  _Float16* ctxP = (_Float16*)(ws + 51380224);
  _Float16* Hm   = (_Float16*)(ws + 59768832);
  float* logits  = (float*)(ws + 63963136);
  float* mech_ws = (float*)(ws + 63979520);
  _Float16* KPp  = xP;   // alias: x packed is dead once proj completes

  hipLaunchKernelGGL(pack_all_kernel, dim3(2304, 2), dim3(256), 0, stream,
                     x, Wq, Wk, Wv, Wo, Wm1, xP, wqP, wkP, wvP, woP, wm1P);

  hipLaunchKernelGGL(proj_kernel, dim3(32, 8, 4), dim3(256), 0, stream,
                     xP, wqP, wkP, wvP, wm1P, bq, bk, bv, bm1, Qh, Kh, Vh, Hm);

  hipLaunchKernelGGL(mech_logits_kernel, dim3(1024), dim3(256), 0, stream,
                     Hm, Wm2, bm2, logits);
  hipLaunchKernelGGL(mech_softmax_kernel, dim3(2), dim3(256), 0, stream,
                     logits, mech_ws, mech_out);

  hipLaunchKernelGGL(kpack_kernel, dim3(2048), dim3(256), 0, stream, Kh, KPp);
  hipLaunchKernelGGL(vpack_kernel, dim3(32, 32), dim3(256), 0, stream, Vh, VP);

  hipLaunchKernelGGL(attn_kernel, dim3(16, 32), dim3(256), 0, stream,
                     Qh, KPp, VP, mech_ws, mask, ctxP);

  hipLaunchKernelGGL(outproj_kernel, dim3(32, 8), dim3(256), 0, stream,
                     ctxP, woP, bo, outp);
}